// Round 9
// baseline (611.707 us; speedup 1.0000x reference)
//
#include <hip/hip_runtime.h>

#define NTOK 4096
#define CHAN 512
#define GSIZE 65536
#define RSQRT2 0.7071067811865476f
#define SCALEX 0.2550348837f        // (1/sqrt(32)) * log2(e); attn uses raw 2^x
#define BAR_OFF 20480
#define WB_OFF 32768
#define QT_OFF (WB_OFF + 2097152)
#define XT_OFF (QT_OFF + 4194304)
#define WS_NEEDED ((size_t)(XT_OFF + 4194304))
#define NBLK 512

typedef unsigned short ushort_t;
typedef __attribute__((ext_vector_type(8))) short bf16x8;
typedef __attribute__((ext_vector_type(8))) _Float16 f16x8;
typedef __attribute__((ext_vector_type(4))) float f32x4;

__device__ __forceinline__ ushort_t f2b(float f) {
    unsigned u = __float_as_uint(f);
    unsigned r = (u + 0x7FFFu + ((u >> 16) & 1u)) >> 16;
    return (ushort_t)r;
}
__device__ __forceinline__ unsigned pack2r(float a, float b) {
    unsigned ua = __float_as_uint(a), ub = __float_as_uint(b);
    return ((ua + 0x8000u) >> 16) | ((ub + 0x8000u) & 0xFFFF0000u);
}
__device__ __forceinline__ unsigned packh2(float a, float b) {
    return __builtin_bit_cast(unsigned, __builtin_amdgcn_cvt_pkrtz(a, b));
}
__device__ __forceinline__ ushort_t f2h(float f) {
    return (ushort_t)(packh2(f, f) & 0xFFFFu);
}
__device__ __forceinline__ bf16x8 ldfrag(const ushort_t* p) {
    return __builtin_bit_cast(bf16x8, *(const uint4*)p);
}
__device__ __forceinline__ f16x8 ldfragh(const ushort_t* p) {
    return __builtin_bit_cast(f16x8, *(const uint4*)p);
}
__device__ __forceinline__ float exp2_raw(float x) {
#if __has_builtin(__builtin_amdgcn_exp2f)
    return __builtin_amdgcn_exp2f(x);
#else
    return __expf(x * 0.6931471805599453f);
#endif
}
__device__ __forceinline__ void ldg2lds16(const void* g, void* l) {
    __builtin_amdgcn_global_load_lds(
        (const __attribute__((address_space(1))) void*)g,
        (__attribute__((address_space(3))) void*)l, 16, 0, 0);
}

// sense-reversing grid barrier; device-scope atomics (cross-XCD safe).
// Requires all NBLK blocks co-resident (2/CU x 256 CU, guaranteed by
// launch_bounds(512,4) VGPR<=128 + LDS 64KB<=80KB).
__device__ __forceinline__ void gridbar(unsigned* cnt, unsigned* gen) {
    __syncthreads();
    if (threadIdx.x == 0) {
        __threadfence();
        unsigned g = __hip_atomic_load(gen, __ATOMIC_ACQUIRE, __HIP_MEMORY_SCOPE_AGENT);
        unsigned a = __hip_atomic_fetch_add(cnt, 1u, __ATOMIC_ACQ_REL, __HIP_MEMORY_SCOPE_AGENT);
        if (a == NBLK - 1) {
            __hip_atomic_store(cnt, 0u, __ATOMIC_RELAXED, __HIP_MEMORY_SCOPE_AGENT);
            __hip_atomic_store(gen, g + 1u, __ATOMIC_RELEASE, __HIP_MEMORY_SCOPE_AGENT);
        } else {
            while (__hip_atomic_load(gen, __ATOMIC_ACQUIRE, __HIP_MEMORY_SCOPE_AGENT) == g)
                __builtin_amdgcn_s_sleep(1);
        }
        __threadfence();
    }
    __syncthreads();
}

__global__ void diag_kernel(float* out, float v) {
    if (threadIdx.x == 0 && blockIdx.x == 0) out[0] = v;
}

// ---- One persistent kernel: 512 blocks x 512 threads, 5 phases, 4 gridbars.
__global__ __launch_bounds__(512, 4) void mega(const float* __restrict__ x,
                                               const float* __restrict__ gnw,
                                               const float* __restrict__ gnb,
                                               const float* __restrict__ wq,
                                               const float* __restrict__ bq,
                                               const float* __restrict__ wk,
                                               const float* __restrict__ bk,
                                               const float* __restrict__ wv,
                                               const float* __restrict__ bv,
                                               const float* __restrict__ wo,
                                               const float* __restrict__ bo,
                                               char* __restrict__ wsb,
                                               float* __restrict__ out) {
    __shared__ __align__(16) char SM[65536];
    int b = blockIdx.x, t = threadIdx.x;
    int w = t >> 6, lane = t & 63, q15 = lane & 15, quad = lane >> 4;

    float* S   = (float*)(wsb + 0);
    float* SS  = (float*)(wsb + 2048);
    float* bqf = (float*)(wsb + 12288);
    float* bkf = (float*)(wsb + 14336);
    float* bvf = (float*)(wsb + 16384);
    unsigned* cnt = (unsigned*)(wsb + BAR_OFF);
    unsigned* gen = cnt + 1;
    ushort_t* Wb = (ushort_t*)(wsb + WB_OFF);
    ushort_t* QT = (ushort_t*)(wsb + QT_OFF);
    ushort_t* xT = (ushort_t*)(wsb + XT_OFF);
    ushort_t* KT = (ushort_t*)out;
    ushort_t* Vb = (ushort_t*)out + (size_t)CHAN * NTOK;

    // ============ P1: gn sums (block = channel) + x transpose/bf16 ============
    {
        const float4* p = (const float4*)(x + (size_t)b * 4096);
        float4 f1 = p[t], f2 = p[t + 512];
        float s = f1.x + f1.y + f1.z + f1.w + f2.x + f2.y + f2.z + f2.w;
        float ss = f1.x * f1.x + f1.y * f1.y + f1.z * f1.z + f1.w * f1.w
                 + f2.x * f2.x + f2.y * f2.y + f2.z * f2.z + f2.w * f2.w;
        #pragma unroll
        for (int off = 32; off > 0; off >>= 1) {
            s += __shfl_xor(s, off);
            ss += __shfl_xor(ss, off);
        }
        float* red = (float*)SM;
        if (lane == 0) { red[w] = s; red[8 + w] = ss; }
        __syncthreads();
        if (t == 0) {
            float a = 0.f, c2 = 0.f;
            #pragma unroll
            for (int i = 0; i < 8; i++) { a += red[i]; c2 += red[8 + i]; }
            S[b] = a; SS[b] = c2;
        }
        // xprep unit b: 64 tokens x 64 chans (8 chans/thread)
        int t0 = (b & 63) << 6;
        int c0 = (b >> 6) << 6;
        int tok = t & 63, c8 = t >> 6;
        float v[8];
        #pragma unroll
        for (int i = 0; i < 8; i++)
            v[i] = x[(size_t)(c0 + c8 * 8 + i) * NTOK + t0 + tok];
        uint4 u;
        u.x = pack2r(v[0], v[1]); u.y = pack2r(v[2], v[3]);
        u.z = pack2r(v[4], v[5]); u.w = pack2r(v[6], v[7]);
        *(uint4*)&xT[(size_t)(t0 + tok) * 512 + c0 + c8 * 8] = u;
    }
    gridbar(cnt, gen);

    // ============ P2: GN coefficients (redundant per block) + weight/bias prep
    {
        float* qaL = (float*)SM;           // [512]
        float* qdL = qaL + 512;
        float* vaL = qaL + 1024;
        float* vdL = qaL + 1536;
        {
            int c = t;
            float Sc = S[c], SSc = SS[c];
            float gs = Sc, gss = SSc;
            #pragma unroll
            for (int off = 1; off < 16; off <<= 1) {
                gs += __shfl_xor(gs, off);
                gss += __shfl_xor(gss, off);
            }
            float mu = gs * (1.f / GSIZE);
            float var = gss * (1.f / GSIZE) - mu * mu;
            float r1 = rsqrtf(var + 1e-6f);
            float wc = gnw[c], bc = gnb[c];
            float a1 = r1 * wc;
            float d1 = bc - mu * a1;
            float S2 = a1 * Sc + 4096.f * d1;
            float SS2 = a1 * a1 * SSc + 2.f * a1 * d1 * Sc + 4096.f * d1 * d1;
            float gs2 = S2, gss2 = SS2;
            #pragma unroll
            for (int off = 1; off < 16; off <<= 1) {
                gs2 += __shfl_xor(gs2, off);
                gss2 += __shfl_xor(gss2, off);
            }
            float mu2 = gs2 * (1.f / GSIZE);
            float var2 = gss2 * (1.f / GSIZE) - mu2 * mu2;
            float r2 = rsqrtf(var2 + 1e-6f);
            float a2 = r2 * wc;
            qaL[c] = a1; qdL[c] = d1;
            vaL[c] = a1 * a2;
            vdL[c] = a2 * (d1 - mu2) + bc;
        }
        __syncthreads();
        auto do_unit = [&](int u) {
            if (u < 192) {   // bias fold, 8 rows (row = u*8 + wave)
                int row = u * 8 + w;
                int m = row >> 9;
                int o = row & 511;
                const float* W = (m == 0) ? wq : (m == 1) ? wk : wv;
                const float* bb = (m == 0) ? bq : (m == 1) ? bk : bv;
                const float* d = (m == 0) ? qdL : vdL;
                float* outp = (m == 0) ? bqf : (m == 1) ? bkf : bvf;
                const float4* wr = (const float4*)(W + (size_t)o * 512) + lane * 2;
                float4 a0 = wr[0], a1 = wr[1];
                float4 d0 = *(const float4*)&d[lane * 8];
                float4 d1 = *(const float4*)&d[lane * 8 + 4];
                float acc = a0.x * d0.x + a0.y * d0.y + a0.z * d0.z + a0.w * d0.w
                          + a1.x * d1.x + a1.y * d1.y + a1.z * d1.z + a1.w * d1.w;
                #pragma unroll
                for (int off = 32; off > 0; off >>= 1) acc += __shfl_xor(acc, off);
                if (lane == 0) outp[o] = bb[o] + acc;
            } else {         // wprep unit k: 2048 elements of matrix y
                int k = u - 192;
                int y = k >> 7;
                const float* src = (y == 0) ? wq : (y == 1) ? wk : (y == 2) ? wv : wo;
                int i = (k & 127) * 2048 + t * 4;
                float4 f = *(const float4*)(src + i);
                if (y < 3) {
                    const float* aff = (y == 0) ? qaL : vaL;
                    int c = i & 511;
                    f.x *= aff[c]; f.y *= aff[c + 1]; f.z *= aff[c + 2]; f.w *= aff[c + 3];
                }
                uint2 uu;
                uu.x = pack2r(f.x, f.y);
                uu.y = pack2r(f.z, f.w);
                *(uint2*)(Wb + (size_t)y * 262144 + i) = uu;
            }
        };
        do_unit(b);
        if (b < 192) do_unit(b + 512);
    }
    gridbar(cnt, gen);

    // ============ P3: QKV projection, 384 blocks, tile 128m x 128n ============
    if (b < 384) {
        ushort_t* SH = (ushort_t*)SM;           // [2][16384]: A 8192 | B 8192
        int nbase = (b & 31) << 7;
        int y = b >> 5;
        int buf = y >> 2;
        int obase = (y & 3) << 7;
        const ushort_t* Wsrc = Wb + (size_t)buf * 262144 + (size_t)obase * 512;
        const float* bias = (buf == 0) ? bqf : (buf == 1) ? bkf : bvf;

        f32x4 acc[8];
        #pragma unroll
        for (int i = 0; i < 8; i++) acc[i] = (f32x4){0.f, 0.f, 0.f, 0.f};

        auto issue = [&](int ck, int bb) {
            ushort_t* base = SH + bb * 16384;
            #pragma unroll
            for (int i = 0; i < 2; i++) {       // A: 1024 slots (128 rows x 8 gran)
                int idx = t + (i << 9);
                int row = idx >> 3, gs = idx & 7;
                int g = gs ^ (row & 7);
                ldg2lds16(&Wsrc[(size_t)row * 512 + ck + g * 8], &base[idx * 8]);
            }
            #pragma unroll
            for (int i = 0; i < 2; i++) {       // B: 1024 slots (128 toks x 8 gran)
                int idx = t + (i << 9);
                int tok = idx >> 3, gs = idx & 7;
                int g = gs ^ (tok & 7);
                ldg2lds16(&xT[(size_t)(nbase + tok) * 512 + ck + g * 8],
                          &base[8192 + idx * 8]);
            }
        };
        issue(0, 0);
        int swz = q15 & 7;
        for (int s = 0; s < 8; s++) {
            int cur = s & 1;
            __syncthreads();
            if (s < 7) issue((s + 1) * 64, cur ^ 1);
            const ushort_t* Wl = SH + cur * 16384;
            const ushort_t* Bn = Wl + 8192;
            #pragma unroll
            for (int kk = 0; kk < 2; kk++) {
                int g = (kk * 4 + quad) ^ swz;
                bf16x8 af = ldfrag(&Wl[((w * 16 + q15) * 8 + g) * 8]);
                #pragma unroll
                for (int n8 = 0; n8 < 8; n8++) {
                    bf16x8 bfv = ldfrag(&Bn[((n8 * 16 + q15) * 8 + g) * 8]);
                    acc[n8] = __builtin_amdgcn_mfma_f32_16x16x32_bf16(af, bfv, acc[n8], 0, 0, 0);
                }
            }
        }
        if (buf == 2) {   // V: f16 [chan][tok]
            #pragma unroll
            for (int r = 0; r < 4; r++) {
                int o = obase + w * 16 + quad * 4 + r;
                float bo_ = bias[o];
                #pragma unroll
                for (int n8 = 0; n8 < 8; n8++)
                    Vb[(size_t)o * NTOK + nbase + n8 * 16 + q15] = f2h(acc[n8][r] + bo_);
            }
        } else {          // Q/K: transpose via Tl (stride 136), flush
            ushort_t* Tl = (ushort_t*)SM;
            __syncthreads();
            float qs = (buf == 0) ? SCALEX : 1.0f;
            #pragma unroll
            for (int r = 0; r < 4; r++) {
                int mloc = w * 16 + quad * 4 + r;
                float bo_ = bias[obase + mloc];
                #pragma unroll
                for (int n8 = 0; n8 < 8; n8++)
                    Tl[(n8 * 16 + q15) * 136 + mloc] = f2b((acc[n8][r] + bo_) * qs);
            }
            __syncthreads();
            ushort_t* dstT = (buf == 0) ? QT : KT;
            #pragma unroll
            for (int i = 0; i < 4; i++) {
                int idx = 4 * t + i;            // 2048 uint4: 128 rows x 16 segs
                int row = idx >> 4, ch = idx & 15;
                uint4 u = *(const uint4*)&Tl[row * 136 + ch * 8];
                *(uint4*)&dstT[(size_t)(nbase + row) * 512 + obase + ch * 8] = u;
            }
        }
    }
    gridbar(cnt, gen);

    // ============ P4: attention (v14 verbatim; 512 blocks) ============
    {
        ushort_t (*KtF)[8192] = (ushort_t(*)[8192])SM;
        ushort_t (*VtF)[8192] = (ushort_t(*)[8192])(SM + 32768);
        int h = b >> 5;
        int qbase = ((b & 31) << 7) + w * 16;
        int hc = h * 32;
        const ushort_t* Vh = Vb + (size_t)hc * NTOK;

        bf16x8 qf = ldfrag(&QT[(size_t)(qbase + q15) * 512 + hc + quad * 8]);

        const uint4 onesu = {0x3C003C00u, 0x3C003C00u, 0x3C003C00u, 0x3C003C00u};
        const f16x8 ones = __builtin_bit_cast(f16x8, onesu);

        f32x4 o[2] = {{0.f, 0.f, 0.f, 0.f}, {0.f, 0.f, 0.f, 0.f}};
        f32x4 lacc = {0.f, 0.f, 0.f, 0.f};

        auto issue = [&](int j0, int bb) {
            #pragma unroll
            for (int i = 0; i < 2; i++) {      // K: 1024 slots
                int sbase = (w << 6) + (i << 9);
                int idx = sbase + lane;
                int krow = idx >> 2;
                int gd = (idx & 3) ^ ((krow >> 1) & 3);
                int rp = krow & 63;
                int srcr = (krow & 192) | (rp & 0x23) | ((rp & 0x0C) << 1) | ((rp & 0x10) >> 2);
                ldg2lds16(&KT[(size_t)(j0 + srcr) * 512 + hc + gd * 8],
                          &KtF[bb][sbase * 8]);
            }
            #pragma unroll
            for (int i = 0; i < 2; i++) {      // V: 1024 slots
                int sbase = (w << 6) + (i << 9);
                int idx = sbase + lane;
                int d = idx >> 5;
                int gd = (idx & 31) ^ (d & 7);
                ldg2lds16(&Vh[(size_t)d * NTOK + j0 + gd * 8],
                          &VtF[bb][sbase * 8]);
            }
        };

        issue(0, 0);
        int ksp8 = (quad ^ ((q15 >> 1) & 3)) * 8;
        int vq = q15 & 7;

        for (int tt = 0; tt < 16; tt++) {
            int cur = tt & 1;
            __syncthreads();
            if (tt < 15) issue((tt + 1) << 8, cur ^ 1);
            const ushort_t* KtC = KtF[cur];
            const ushort_t* VtC = VtF[cur];

            #pragma unroll
            for (int h2 = 0; h2 < 4; h2++) {
                f32x4 st[4];
                __builtin_amdgcn_s_setprio(1);
                #pragma unroll
                for (int kt = 0; kt < 4; kt++) {
                    bf16x8 kf = ldfrag(&KtC[(h2 * 64 + kt * 16 + q15) * 32 + ksp8]);
                    f32x4 z = {0.f, 0.f, 0.f, 0.f};
                    st[kt] = __builtin_amdgcn_mfma_f32_16x16x32_bf16(kf, qf, z, 0, 0, 0);
                }
                __builtin_amdgcn_s_setprio(0);

                #pragma unroll
                for (int kt = 0; kt < 4; kt++)
                    #pragma unroll
                    for (int r = 0; r < 4; r++)
                        st[kt][r] = exp2_raw(st[kt][r]);

                int g0 = ((h2 * 8 + quad) ^ vq) * 8;
                int g1 = g0 ^ 32;
                f16x8 v00 = ldfragh(&VtC[q15 * 256 + g0]);
                f16x8 v01 = ldfragh(&VtC[(16 + q15) * 256 + g0]);
                f16x8 v10 = ldfragh(&VtC[q15 * 256 + g1]);
                f16x8 v11 = ldfragh(&VtC[(16 + q15) * 256 + g1]);

                uint4 p0u, p1u;
                p0u.x = packh2(st[0][0], st[0][1]);
                p0u.y = packh2(st[0][2], st[0][3]);
                p0u.z = packh2(st[1][0], st[1][1]);
                p0u.w = packh2(st[1][2], st[1][3]);
                p1u.x = packh2(st[2][0], st[2][1]);
                p1u.y = packh2(st[2][2], st[2][3]);
                p1u.z = packh2(st[3][0], st[3][1]);
                p1u.w = packh2(st[3][2], st[3][3]);
                f16x8 pf0 = __builtin_bit_cast(f16x8, p0u);
                f16x8 pf1 = __builtin_bit_cast(f16x8, p1u);
                __builtin_amdgcn_s_setprio(1);
                o[0] = __builtin_amdgcn_mfma_f32_16x16x32_f16(pf0, v00, o[0], 0, 0, 0);
                o[1] = __builtin_amdgcn_mfma_f32_16x16x32_f16(pf0, v01, o[1], 0, 0, 0);
                lacc = __builtin_amdgcn_mfma_f32_16x16x32_f16(pf0, ones, lacc, 0, 0, 0);
                o[0] = __builtin_amdgcn_mfma_f32_16x16x32_f16(pf1, v10, o[0], 0, 0, 0);
                o[1] = __builtin_amdgcn_mfma_f32_16x16x32_f16(pf1, v11, o[1], 0, 0, 0);
                lacc = __builtin_amdgcn_mfma_f32_16x16x32_f16(pf1, ones, lacc, 0, 0, 0);
                __builtin_amdgcn_s_setprio(0);
            }
        }

        #pragma unroll
        for (int r = 0; r < 4; r++) {
            float li = 1.f / lacc[r];
            int q = quad * 4 + r;
            QT[(size_t)(qbase + q) * 512 + hc + q15]      = f2b(o[0][r] * li);
            QT[(size_t)(qbase + q) * 512 + hc + 16 + q15] = f2b(o[1][r] * li);
        }
    }
    gridbar(cnt, gen);

    // ============ P5: output projection, 256 blocks, tile 64o x 128n ============
    if (b < 256) {
        ushort_t* Wl = (ushort_t*)SM;                    // [64][72]
        ushort_t* Bn = (ushort_t*)SM + 4608;             // [128][72]
        const ushort_t* Wob = Wb + (size_t)3 * 262144;
        int nbase = (b & 31) << 7;
        int obase = (b >> 5) << 6;
        int w4 = w & 3, nh = w >> 2;

        f32x4 acc[4];
        #pragma unroll
        for (int i = 0; i < 4; i++) acc[i] = (f32x4){0.f, 0.f, 0.f, 0.f};

        for (int ck = 0; ck < 512; ck += 64) {
            __syncthreads();
            {   // Wl: 512 uint4
                int row = t >> 3, seg = t & 7;
                *(uint4*)&Wl[(row * 72) + seg * 8] =
                    *(const uint4*)&Wob[(size_t)(obase + row) * 512 + ck + seg * 8];
            }
            #pragma unroll
            for (int i = 0; i < 2; i++) {    // Bn: 1024 uint4
                int idx = t + (i << 9);
                int row = idx >> 3, seg = idx & 7;
                *(uint4*)&Bn[(row * 72) + seg * 8] =
                    *(const uint4*)&QT[(size_t)(nbase + row) * 512 + ck + seg * 8];
            }
            __syncthreads();
            #pragma unroll
            for (int kk = 0; kk < 2; kk++) {
                bf16x8 af = ldfrag(&Wl[(w4 * 16 + q15) * 72 + kk * 32 + quad * 8]);
                #pragma unroll
                for (int n8 = 0; n8 < 4; n8++) {
                    bf16x8 bfv = ldfrag(&Bn[(nh * 64 + n8 * 16 + q15) * 72 + kk * 32 + quad * 8]);
                    acc[n8] = __builtin_amdgcn_mfma_f32_16x16x32_bf16(af, bfv, acc[n8], 0, 0, 0);
                }
            }
        }

        #pragma unroll
        for (int r = 0; r < 4; r++) {
            int o = obase + w4 * 16 + quad * 4 + r;
            float bb = bo[o];
            #pragma unroll
            for (int n8 = 0; n8 < 4; n8++) {
                size_t idx = (size_t)o * NTOK + nbase + nh * 64 + n8 * 16 + q15;
                out[idx] = (acc[n8][r] + bb + x[idx]) * RSQRT2;
            }
        }
    }
}

extern "C" void kernel_launch(void* const* d_in, const int* in_sizes, int n_in,
                              void* d_out, int out_size, void* d_ws, size_t ws_size,
                              hipStream_t stream) {
    const float* x   = (const float*)d_in[0];
    const float* gnw = (const float*)d_in[1];
    const float* gnb = (const float*)d_in[2];
    const float* wq  = (const float*)d_in[3];
    const float* bq  = (const float*)d_in[4];
    const float* wk  = (const float*)d_in[5];
    const float* bk  = (const float*)d_in[6];
    const float* wv  = (const float*)d_in[7];
    const float* bv  = (const float*)d_in[8];
    const float* wo  = (const float*)d_in[9];
    const float* bo  = (const float*)d_in[10];
    float* out = (float*)d_out;

    if (ws_size < WS_NEEDED) {
        diag_kernel<<<1, 64, 0, stream>>>(out, (float)(ws_size >> 16));
        return;
    }

    char* wsb = (char*)d_ws;
    hipMemsetAsync(wsb + BAR_OFF, 0, 8, stream);   // barrier cnt/gen
    mega<<<NBLK, 512, 0, stream>>>(x, gnw, gnb, wq, bq, wk, bk, wv, bv, wo, bo,
                                   wsb, out);
}

// Round 10
// 156.066 us; speedup vs baseline: 3.9195x; 3.9195x over previous
//
#include <hip/hip_runtime.h>

#define NTOK 4096
#define CHAN 512
#define GSIZE 65536
#define RSQRT2 0.7071067811865476f
#define SCALEX 0.2550348837f        // (1/sqrt(32)) * log2(e); attn uses raw 2^x
#define WB_OFF 32768
#define QT_OFF (WB_OFF + 2097152)
#define XT_OFF (QT_OFF + 4194304)
#define WS_NEEDED ((size_t)(XT_OFF + 4194304))

typedef unsigned short ushort_t;
typedef __attribute__((ext_vector_type(8))) short bf16x8;
typedef __attribute__((ext_vector_type(8))) _Float16 f16x8;
typedef __attribute__((ext_vector_type(4))) float f32x4;

__device__ __forceinline__ ushort_t f2b(float f) {
    unsigned u = __float_as_uint(f);
    unsigned r = (u + 0x7FFFu + ((u >> 16) & 1u)) >> 16;
    return (ushort_t)r;
}
__device__ __forceinline__ unsigned pack2r(float a, float b) {
    unsigned ua = __float_as_uint(a), ub = __float_as_uint(b);
    return ((ua + 0x8000u) >> 16) | ((ub + 0x8000u) & 0xFFFF0000u);
}
__device__ __forceinline__ unsigned packh2(float a, float b) {
    return __builtin_bit_cast(unsigned, __builtin_amdgcn_cvt_pkrtz(a, b));
}
__device__ __forceinline__ ushort_t f2h(float f) {
    return (ushort_t)(packh2(f, f) & 0xFFFFu);
}
__device__ __forceinline__ bf16x8 ldfrag(const ushort_t* p) {
    return __builtin_bit_cast(bf16x8, *(const uint4*)p);
}
__device__ __forceinline__ f16x8 ldfragh(const ushort_t* p) {
    return __builtin_bit_cast(f16x8, *(const uint4*)p);
}
__device__ __forceinline__ float exp2_raw(float x) {
#if __has_builtin(__builtin_amdgcn_exp2f)
    return __builtin_amdgcn_exp2f(x);
#else
    return __expf(x * 0.6931471805599453f);
#endif
}
__device__ __forceinline__ void ldg2lds16(const void* g, void* l) {
    __builtin_amdgcn_global_load_lds(
        (const __attribute__((address_space(1))) void*)g,
        (__attribute__((address_space(3))) void*)l, 16, 0, 0);
}

__global__ void diag_kernel(float* out, float v) {
    if (threadIdx.x == 0 && blockIdx.x == 0) out[0] = v;
}

// ---- K1: GN channel sums + x transpose/bf16 (fused; block = channel = xprep unit).
__global__ __launch_bounds__(512) void sums_xprep(const float* __restrict__ x,
                                                  float* __restrict__ S,
                                                  float* __restrict__ SS,
                                                  ushort_t* __restrict__ xT) {
    __shared__ float red[16];
    int b = blockIdx.x, t = threadIdx.x;
    int w = t >> 6, lane = t & 63;
    const float4* p = (const float4*)(x + (size_t)b * 4096);
    float4 f1 = p[t], f2 = p[t + 512];
    float s = f1.x + f1.y + f1.z + f1.w + f2.x + f2.y + f2.z + f2.w;
    float ss = f1.x * f1.x + f1.y * f1.y + f1.z * f1.z + f1.w * f1.w
             + f2.x * f2.x + f2.y * f2.y + f2.z * f2.z + f2.w * f2.w;
    #pragma unroll
    for (int off = 32; off > 0; off >>= 1) {
        s += __shfl_xor(s, off);
        ss += __shfl_xor(ss, off);
    }
    if (lane == 0) { red[w] = s; red[8 + w] = ss; }
    __syncthreads();
    if (t == 0) {
        float a = 0.f, c2 = 0.f;
        #pragma unroll
        for (int i = 0; i < 8; i++) { a += red[i]; c2 += red[8 + i]; }
        S[b] = a; SS[b] = c2;
    }
    // xprep unit b: 64 tokens x 64 chans (8 chans/thread)
    int t0 = (b & 63) << 6;
    int c0 = (b >> 6) << 6;
    int tok = t & 63, c8 = t >> 6;
    float v[8];
    #pragma unroll
    for (int i = 0; i < 8; i++)
        v[i] = x[(size_t)(c0 + c8 * 8 + i) * NTOK + t0 + tok];
    uint4 u;
    u.x = pack2r(v[0], v[1]); u.y = pack2r(v[2], v[3]);
    u.z = pack2r(v[4], v[5]); u.w = pack2r(v[6], v[7]);
    *(uint4*)&xT[(size_t)(t0 + tok) * 512 + c0 + c8 * 8] = u;
}

// ---- K2: GN coefficients (redundant per block, in LDS) + bias_fold/wprep.
// Grid 704: blocks 0..191 = bias fold (8 rows each); 192..703 = wprep units.
__global__ __launch_bounds__(512) void coef_prep(const float* __restrict__ S,
                                                 const float* __restrict__ SS,
                                                 const float* __restrict__ gnw,
                                                 const float* __restrict__ gnb,
                                                 const float* __restrict__ wq,
                                                 const float* __restrict__ wk,
                                                 const float* __restrict__ wv,
                                                 const float* __restrict__ wo,
                                                 const float* __restrict__ bq,
                                                 const float* __restrict__ bk,
                                                 const float* __restrict__ bv,
                                                 float* __restrict__ bqf,
                                                 float* __restrict__ bkf,
                                                 float* __restrict__ bvf,
                                                 ushort_t* __restrict__ Wb) {
    __shared__ float qaL[512], qdL[512], vaL[512], vdL[512];
    int b = blockIdx.x, t = threadIdx.x;
    int w = t >> 6, lane = t & 63;
    {
        int c = t;
        float Sc = S[c], SSc = SS[c];
        float gs = Sc, gss = SSc;
        #pragma unroll
        for (int off = 1; off < 16; off <<= 1) {
            gs += __shfl_xor(gs, off);
            gss += __shfl_xor(gss, off);
        }
        float mu = gs * (1.f / GSIZE);
        float var = gss * (1.f / GSIZE) - mu * mu;
        float r1 = rsqrtf(var + 1e-6f);
        float wc = gnw[c], bc = gnb[c];
        float a1 = r1 * wc;
        float d1 = bc - mu * a1;
        float S2 = a1 * Sc + 4096.f * d1;
        float SS2 = a1 * a1 * SSc + 2.f * a1 * d1 * Sc + 4096.f * d1 * d1;
        float gs2 = S2, gss2 = SS2;
        #pragma unroll
        for (int off = 1; off < 16; off <<= 1) {
            gs2 += __shfl_xor(gs2, off);
            gss2 += __shfl_xor(gss2, off);
        }
        float mu2 = gs2 * (1.f / GSIZE);
        float var2 = gss2 * (1.f / GSIZE) - mu2 * mu2;
        float r2 = rsqrtf(var2 + 1e-6f);
        float a2 = r2 * wc;
        qaL[c] = a1; qdL[c] = d1;
        vaL[c] = a1 * a2;
        vdL[c] = a2 * (d1 - mu2) + bc;
    }
    __syncthreads();
    if (b < 192) {       // bias fold: b'[o] = b[o] + sum_c W[o][c]*d[c]
        int row = b * 8 + w;
        int m = row >> 9;
        int o = row & 511;
        const float* W = (m == 0) ? wq : (m == 1) ? wk : wv;
        const float* bb = (m == 0) ? bq : (m == 1) ? bk : bv;
        const float* d = (m == 0) ? qdL : vdL;
        float* outp = (m == 0) ? bqf : (m == 1) ? bkf : bvf;
        const float4* wr = (const float4*)(W + (size_t)o * 512) + lane * 2;
        float4 a0 = wr[0], a1 = wr[1];
        float4 d0 = *(const float4*)&d[lane * 8];
        float4 d1 = *(const float4*)&d[lane * 8 + 4];
        float acc = a0.x * d0.x + a0.y * d0.y + a0.z * d0.z + a0.w * d0.w
                  + a1.x * d1.x + a1.y * d1.y + a1.z * d1.z + a1.w * d1.w;
        #pragma unroll
        for (int off = 32; off > 0; off >>= 1) acc += __shfl_xor(acc, off);
        if (lane == 0) outp[o] = bb[o] + acc;
    } else {             // wprep unit k: 2048 elements of matrix y
        int k = b - 192;
        int y = k >> 7;
        const float* src = (y == 0) ? wq : (y == 1) ? wk : (y == 2) ? wv : wo;
        int i = (k & 127) * 2048 + t * 4;
        float4 f = *(const float4*)(src + i);
        if (y < 3) {
            const float* aff = (y == 0) ? qaL : vaL;
            int c = i & 511;
            f.x *= aff[c]; f.y *= aff[c + 1]; f.z *= aff[c + 2]; f.w *= aff[c + 3];
        }
        uint2 uu;
        uu.x = pack2r(f.x, f.y);
        uu.y = pack2r(f.z, f.w);
        *(uint2*)(Wb + (size_t)y * 262144 + i) = uu;
    }
}

// ---- K3: QKV projection, tile 128m x 128n, 512 thr, grid (32, 12).
// Both operands DMA-staged, double-buffered, source-XOR-swizzled (mega-P3,
// hardware-verified correct in round 8).
__global__ __launch_bounds__(512, 4) void qkv_mfma(const ushort_t* __restrict__ xT,
                                                   const ushort_t* __restrict__ Wb,
                                                   const float* __restrict__ bqf,
                                                   const float* __restrict__ bkf,
                                                   const float* __restrict__ bvf,
                                                   ushort_t* __restrict__ QT,
                                                   ushort_t* __restrict__ KT,
                                                   ushort_t* __restrict__ Vb) {
    __shared__ __align__(16) ushort_t SH[2][16384];  // [buf][A 8192 | B 8192]
    int t = threadIdx.x;
    int nbase = blockIdx.x << 7;
    int y = blockIdx.y;
    int buf = y >> 2;
    int obase = (y & 3) << 7;
    const ushort_t* Wsrc = Wb + (size_t)buf * 262144 + (size_t)obase * 512;
    const float* bias = (buf == 0) ? bqf : (buf == 1) ? bkf : bvf;

    int w = t >> 6, lane = t & 63, q15 = lane & 15, quad = lane >> 4;
    f32x4 acc[8];
    #pragma unroll
    for (int i = 0; i < 8; i++) acc[i] = (f32x4){0.f, 0.f, 0.f, 0.f};

    auto issue = [&](int ck, int bb) {
        ushort_t* base = SH[bb];
        #pragma unroll
        for (int i = 0; i < 2; i++) {       // A: 1024 slots (128 rows x 8 gran)
            int idx = t + (i << 9);
            int row = idx >> 3, gs = idx & 7;
            int g = gs ^ (row & 7);
            ldg2lds16(&Wsrc[(size_t)row * 512 + ck + g * 8], &base[idx * 8]);
        }
        #pragma unroll
        for (int i = 0; i < 2; i++) {       // B: 1024 slots (128 toks x 8 gran)
            int idx = t + (i << 9);
            int tok = idx >> 3, gs = idx & 7;
            int g = gs ^ (tok & 7);
            ldg2lds16(&xT[(size_t)(nbase + tok) * 512 + ck + g * 8],
                      &base[8192 + idx * 8]);
        }
    };
    issue(0, 0);
    int swz = q15 & 7;
    for (int s = 0; s < 8; s++) {
        int cur = s & 1;
        __syncthreads();
        if (s < 7) issue((s + 1) * 64, cur ^ 1);
        const ushort_t* Wl = SH[cur];
        const ushort_t* Bn = SH[cur] + 8192;
        #pragma unroll
        for (int kk = 0; kk < 2; kk++) {
            int g = (kk * 4 + quad) ^ swz;
            bf16x8 af = ldfrag(&Wl[((w * 16 + q15) * 8 + g) * 8]);
            #pragma unroll
            for (int n8 = 0; n8 < 8; n8++) {
                bf16x8 bfv = ldfrag(&Bn[((n8 * 16 + q15) * 8 + g) * 8]);
                acc[n8] = __builtin_amdgcn_mfma_f32_16x16x32_bf16(af, bfv, acc[n8], 0, 0, 0);
            }
        }
    }
    if (buf == 2) {   // V: f16 [chan][tok]
        #pragma unroll
        for (int r = 0; r < 4; r++) {
            int o = obase + w * 16 + quad * 4 + r;
            float bo_ = bias[o];
            #pragma unroll
            for (int n8 = 0; n8 < 8; n8++)
                Vb[(size_t)o * NTOK + nbase + n8 * 16 + q15] = f2h(acc[n8][r] + bo_);
        }
    } else {          // Q/K: transpose via Tl (stride 136), flush
        ushort_t* Tl = SH[0];
        __syncthreads();
        float qs = (buf == 0) ? SCALEX : 1.0f;
        #pragma unroll
        for (int r = 0; r < 4; r++) {
            int mloc = w * 16 + quad * 4 + r;
            float bo_ = bias[obase + mloc];
            #pragma unroll
            for (int n8 = 0; n8 < 8; n8++)
                Tl[(n8 * 16 + q15) * 136 + mloc] = f2b((acc[n8][r] + bo_) * qs);
        }
        __syncthreads();
        ushort_t* dstT = (buf == 0) ? QT : KT;
        #pragma unroll
        for (int i = 0; i < 4; i++) {
            int idx = 4 * t + i;            // 2048 uint4: 128 rows x 16 segs
            int row = idx >> 4, ch = idx & 15;
            uint4 u = *(const uint4*)&Tl[row * 136 + ch * 8];
            *(uint4*)&dstT[(size_t)(nbase + row) * 512 + obase + ch * 8] = u;
        }
    }
}

// ---- K4: attention v14 (proven 53.4 us) — untouched.
__global__ __launch_bounds__(512, 4) void attn_v14(ushort_t* __restrict__ QT,
                                                   const ushort_t* __restrict__ KT,
                                                   const ushort_t* __restrict__ V) {
    __shared__ __align__(16) ushort_t KtF[2][8192];
    __shared__ __align__(16) ushort_t VtF[2][8192];
    int h = blockIdx.y;
    int t = threadIdx.x;
    int w = t >> 6, lane = t & 63, q15 = lane & 15, quad = lane >> 4;
    int qbase = (blockIdx.x << 7) + w * 16;
    int hc = h * 32;
    const ushort_t* Vh = V + (size_t)hc * NTOK;

    bf16x8 qf = ldfrag(&QT[(size_t)(qbase + q15) * 512 + hc + quad * 8]);

    const uint4 onesu = {0x3C003C00u, 0x3C003C00u, 0x3C003C00u, 0x3C003C00u};
    const f16x8 ones = __builtin_bit_cast(f16x8, onesu);

    f32x4 o[2] = {{0.f, 0.f, 0.f, 0.f}, {0.f, 0.f, 0.f, 0.f}};
    f32x4 lacc = {0.f, 0.f, 0.f, 0.f};

    auto issue = [&](int j0, int b) {
        #pragma unroll
        for (int i = 0; i < 2; i++) {      // K: 1024 slots
            int sbase = (w << 6) + (i << 9);
            int idx = sbase + lane;
            int krow = idx >> 2;
            int gd = (idx & 3) ^ ((krow >> 1) & 3);
            int rp = krow & 63;            // key permutation (register-direct P)
            int srcr = (krow & 192) | (rp & 0x23) | ((rp & 0x0C) << 1) | ((rp & 0x10) >> 2);
            ldg2lds16(&KT[(size_t)(j0 + srcr) * 512 + hc + gd * 8],
                      &KtF[b][sbase * 8]);
        }
        #pragma unroll
        for (int i = 0; i < 2; i++) {      // V: 1024 slots
            int sbase = (w << 6) + (i << 9);
            int idx = sbase + lane;
            int d = idx >> 5;
            int gd = (idx & 31) ^ (d & 7);
            ldg2lds16(&Vh[(size_t)d * NTOK + j0 + gd * 8],
                      &VtF[b][sbase * 8]);
        }
    };

    issue(0, 0);
    int ksp8 = (quad ^ ((q15 >> 1) & 3)) * 8;
    int vq = q15 & 7;

    for (int tt = 0; tt < 16; tt++) {
        int cur = tt & 1;
        __syncthreads();
        if (tt < 15) issue((tt + 1) << 8, cur ^ 1);
        const ushort_t* KtC = KtF[cur];
        const ushort_t* VtC = VtF[cur];

        #pragma unroll
        for (int h2 = 0; h2 < 4; h2++) {
            f32x4 st[4];
            __builtin_amdgcn_s_setprio(1);
            #pragma unroll
            for (int kt = 0; kt < 4; kt++) {
                bf16x8 kf = ldfrag(&KtC[(h2 * 64 + kt * 16 + q15) * 32 + ksp8]);
                f32x4 z = {0.f, 0.f, 0.f, 0.f};
                st[kt] = __builtin_amdgcn_mfma_f32_16x16x32_bf16(kf, qf, z, 0, 0, 0);
            }
            __builtin_amdgcn_s_setprio(0);

            #pragma unroll
            for (int kt = 0; kt < 4; kt++)
                #pragma unroll
                for (int r = 0; r < 4; r++)
                    st[kt][r] = exp2_raw(st[kt][r]);

            int g0 = ((h2 * 8 + quad) ^ vq) * 8;
            int g1 = g0 ^ 32;
            f16x8 v00 = ldfragh(&VtC[q15 * 256 + g0]);
            f16x8 v01 = ldfragh(&VtC[(16 + q15) * 256 + g0]);
            f16x8 v10 = ldfragh(&VtC[q15 * 256 + g1]);
            f16x8 v11 = ldfragh(&VtC[(16 + q15) * 256 + g1]);

            uint4 p0u, p1u;
            p0u.x = packh2(st[0][0], st[0][1]);
            p0u.y = packh2(st[0][2], st[0][3]);
            p0u.z = packh2(st[1][0], st[1][1]);
            p0u.w = packh2(st[1][2], st[1][3]);
            p1u.x = packh2(st[2][0], st[2][1]);
            p1u.y = packh2(st[2][2], st[2][3]);
            p1u.z = packh2(st[3][0], st[3][1]);
            p1u.w = packh2(st[3][2], st[3][3]);
            f16x8 pf0 = __builtin_bit_cast(f16x8, p0u);
            f16x8 pf1 = __builtin_bit_cast(f16x8, p1u);
            __builtin_amdgcn_s_setprio(1);
            o[0] = __builtin_amdgcn_mfma_f32_16x16x32_f16(pf0, v00, o[0], 0, 0, 0);
            o[1] = __builtin_amdgcn_mfma_f32_16x16x32_f16(pf0, v01, o[1], 0, 0, 0);
            lacc = __builtin_amdgcn_mfma_f32_16x16x32_f16(pf0, ones, lacc, 0, 0, 0);
            o[0] = __builtin_amdgcn_mfma_f32_16x16x32_f16(pf1, v10, o[0], 0, 0, 0);
            o[1] = __builtin_amdgcn_mfma_f32_16x16x32_f16(pf1, v11, o[1], 0, 0, 0);
            lacc = __builtin_amdgcn_mfma_f32_16x16x32_f16(pf1, ones, lacc, 0, 0, 0);
            __builtin_amdgcn_s_setprio(0);
        }
    }

    #pragma unroll
    for (int r = 0; r < 4; r++) {
        float li = 1.f / lacc[r];
        int q = quad * 4 + r;
        QT[(size_t)(qbase + q) * 512 + hc + q15]      = f2b(o[0][r] * li);
        QT[(size_t)(qbase + q) * 512 + hc + 16 + q15] = f2b(o[1][r] * li);
    }
}

// ---- K5: output projection, tile 64o x 128n, 512 thr, grid (32, 8)
// (mega-P5, hardware-verified correct in round 8).
__global__ __launch_bounds__(512) void oproj_mfma(const ushort_t* __restrict__ OT,
                                                  const ushort_t* __restrict__ Wob,
                                                  const float* __restrict__ bo,
                                                  const float* __restrict__ x,
                                                  float* __restrict__ out) {
    __shared__ __align__(16) ushort_t Wl[64][72];
    __shared__ __align__(16) ushort_t Bn[128][72];
    int t = threadIdx.x;
    int nbase = blockIdx.x << 7;
    int obase = blockIdx.y << 6;
    int w = t >> 6, lane = t & 63, q15 = lane & 15, quad = lane >> 4;
    int w4 = w & 3, nh = w >> 2;

    f32x4 acc[4];
    #pragma unroll
    for (int i = 0; i < 4; i++) acc[i] = (f32x4){0.f, 0.f, 0.f, 0.f};

    for (int ck = 0; ck < 512; ck += 64) {
        __syncthreads();
        {   // Wl: 512 uint4
            int row = t >> 3, seg = t & 7;
            *(uint4*)&Wl[row][seg * 8] =
                *(const uint4*)&Wob[(size_t)(obase + row) * 512 + ck + seg * 8];
        }
        #pragma unroll
        for (int i = 0; i < 2; i++) {    // Bn: 1024 uint4
            int idx = t + (i << 9);
            int row = idx >> 3, seg = idx & 7;
            *(uint4*)&Bn[row][seg * 8] =
                *(const uint4*)&OT[(size_t)(nbase + row) * 512 + ck + seg * 8];
        }
        __syncthreads();
        #pragma unroll
        for (int kk = 0; kk < 2; kk++) {
            bf16x8 af = ldfrag(&Wl[w4 * 16 + q15][kk * 32 + quad * 8]);
            #pragma unroll
            for (int n8 = 0; n8 < 4; n8++) {
                bf16x8 bfv = ldfrag(&Bn[nh * 64 + n8 * 16 + q15][kk * 32 + quad * 8]);
                acc[n8] = __builtin_amdgcn_mfma_f32_16x16x32_bf16(af, bfv, acc[n8], 0, 0, 0);
            }
        }
    }

    #pragma unroll
    for (int r = 0; r < 4; r++) {
        int o = obase + w4 * 16 + quad * 4 + r;
        float bb = bo[o];
        #pragma unroll
        for (int n8 = 0; n8 < 4; n8++) {
            size_t idx = (size_t)o * NTOK + nbase + nh * 64 + n8 * 16 + q15;
            out[idx] = (acc[n8][r] + bb + x[idx]) * RSQRT2;
        }
    }
}

extern "C" void kernel_launch(void* const* d_in, const int* in_sizes, int n_in,
                              void* d_out, int out_size, void* d_ws, size_t ws_size,
                              hipStream_t stream) {
    const float* x   = (const float*)d_in[0];
    const float* gnw = (const float*)d_in[1];
    const float* gnb = (const float*)d_in[2];
    const float* wq  = (const float*)d_in[3];
    const float* bq  = (const float*)d_in[4];
    const float* wk  = (const float*)d_in[5];
    const float* bk  = (const float*)d_in[6];
    const float* wv  = (const float*)d_in[7];
    const float* bv  = (const float*)d_in[8];
    const float* wo  = (const float*)d_in[9];
    const float* bo  = (const float*)d_in[10];
    float* out = (float*)d_out;

    if (ws_size < WS_NEEDED) {
        diag_kernel<<<1, 64, 0, stream>>>(out, (float)(ws_size >> 16));
        return;
    }

    char* wsb = (char*)d_ws;
    float* S   = (float*)(wsb + 0);
    float* SS  = (float*)(wsb + 2048);
    float* bqf = (float*)(wsb + 12288);
    float* bkf = (float*)(wsb + 14336);
    float* bvf = (float*)(wsb + 16384);
    ushort_t* Wb = (ushort_t*)(wsb + WB_OFF);    // 2 MB bf16 (wq'|wk'|wv'|wo)
    ushort_t* QT = (ushort_t*)(wsb + QT_OFF);    // 4 MB bf16 [4096][512] (becomes O)
    ushort_t* xT = (ushort_t*)(wsb + XT_OFF);    // 4 MB bf16 [4096][512]
    ushort_t* KT = (ushort_t*)d_out;                        // 4 MB bf16 [4096][512]
    ushort_t* Vb = (ushort_t*)d_out + (size_t)CHAN * NTOK;  // 4 MB f16 [512][4096]

    sums_xprep<<<512, 512, 0, stream>>>(x, S, SS, xT);
    coef_prep<<<704, 512, 0, stream>>>(S, SS, gnw, gnb, wq, wk, wv, wo,
                                       bq, bk, bv, bqf, bkf, bvf, Wb);
    qkv_mfma<<<dim3(32, 12), 512, 0, stream>>>(xT, Wb, bqf, bkf, bvf, QT, KT, Vb);
    attn_v14<<<dim3(32, 16), 512, 0, stream>>>(QT, KT, Vb);
    oproj_mfma<<<dim3(32, 8), 512, 0, stream>>>(QT, Wb + (size_t)3 * 262144, bo, x, out);
}